// Round 8
// baseline (280.251 us; speedup 1.0000x reference)
//
#include <hip/hip_runtime.h>
#include <hip/hip_bf16.h>
#include <stdint.h>

typedef short short8 __attribute__((ext_vector_type(8)));
typedef float f32x4 __attribute__((ext_vector_type(4)));

#define NB    32
#define NC    512
#define NHD   8
#define HDD   64
#define N7    49
#define RES   56
#define P56   3136
#define NTOK  1568     // 32*49
#define NTOKP 1664     // padded to 13*128 for unguarded staging
#define NBIG  100352   // 32*3136
#define KDIM  512
#define KLOC  576      // 64ci * 9taps

// async global->LDS, 16B per lane; LDS dest is wave-uniform base + lane*16
__device__ __forceinline__ void gload_lds16(const __hip_bfloat16* g, __hip_bfloat16* l) {
  __builtin_amdgcn_global_load_lds(
      (const __attribute__((address_space(1))) void*)g,
      (__attribute__((address_space(3))) void*)l, 16, 0, 0);
}

// ---------------------------------------------------------------- K0: fp32 -> bf16 weight convert (4x 512x512 + loc_w 512x576)
__global__ __launch_bounds__(256) void k_cvt(
    const float* __restrict__ s0, const float* __restrict__ s1,
    const float* __restrict__ s2, const float* __restrict__ s3,
    const float* __restrict__ s4,
    __hip_bfloat16* __restrict__ d0, __hip_bfloat16* __restrict__ d1,
    __hip_bfloat16* __restrict__ d2, __hip_bfloat16* __restrict__ d3,
    __hip_bfloat16* __restrict__ d4) {
  const float* s; __hip_bfloat16* d; int n = NC * NC;
  switch (blockIdx.y) {
    case 0: s = s0; d = d0; break;
    case 1: s = s1; d = d1; break;
    case 2: s = s2; d = d2; break;
    case 3: s = s3; d = d3; break;
    default: s = s4; d = d4; n = NC * KLOC; break;
  }
  for (int i = blockIdx.x * blockDim.x + threadIdx.x; i < n; i += gridDim.x * blockDim.x)
    d[i] = __float2bfloat16(s[i]);
}

// ---------------------------------------------------------------- K1: depthwise 3x3 stride-8 + BN0 -> xs[1568][512] bf16
__global__ __launch_bounds__(64) void k_stride(
    const float* __restrict__ x, const float* __restrict__ dw,
    const float* __restrict__ s0, const float* __restrict__ b0,
    __hip_bfloat16* __restrict__ xs) {
  const int ci = blockIdx.x, b = blockIdx.y, t = threadIdx.x;
  __shared__ float rows[21][56];
  const float* xp = x + ((size_t)(b * NC + ci)) * RES * RES;
  for (int r = t; r < 21 * 56; r += 64) {
    int rr = r / 56, cc = r - rr * 56;
    int oh = rr / 3, kh = rr - oh * 3;
    int ih = oh * 8 + kh - 1;
    rows[rr][cc] = (ih >= 0) ? xp[ih * 56 + cc] : 0.f;
  }
  float w[9];
#pragma unroll
  for (int j = 0; j < 9; ++j) w[j] = dw[ci * 9 + j];
  const float sc = s0[ci], bi = b0[ci];
  __syncthreads();
  if (t < 49) {
    const int oh = t / 7, ow = t - oh * 7;
    float acc = 0.f;
#pragma unroll
    for (int kh = 0; kh < 3; ++kh)
#pragma unroll
      for (int kw = 0; kw < 3; ++kw) {
        int col = ow * 8 + kw - 1;
        float v = (col >= 0) ? rows[oh * 3 + kh][col] : 0.f;
        acc += v * w[kh * 3 + kw];
      }
    xs[(size_t)(b * 49 + t) * NC + ci] = __float2bfloat16(acc * sc + bi);
  }
}

// ---------------------------------------------------------------- BIG GEMM: 128x128 tile, BK=32, 2-deep counted vmcnt, T2 swizzle,
// 32 KB LDS -> ~4 blocks/CU (epilogue/barrier overlap across blocks).
// M=512, N=100352, K=512. grid = 4*784 = 3136 x 256 threads.
__global__ __launch_bounds__(256) void k_gemm_big(
    const __hip_bfloat16* __restrict__ A,    // [512][512] bf16
    const __hip_bfloat16* __restrict__ Bm,   // [100352][512] bf16
    const float* __restrict__ scale, const float* __restrict__ bias,
    float* __restrict__ out) {
  __shared__ __align__(16) __hip_bfloat16 lsA[2][128 * 32];
  __shared__ __align__(16) __hip_bfloat16 lsB[2][128 * 32];
  const int t = threadIdx.x;
  // XCD swizzle: 3136 % 8 == 0 -> chunked bijective; 4 m-tiles per B panel adjacent
  const int cpx = gridDim.x >> 3;
  const int nid = (blockIdx.x & 7) * cpx + (blockIdx.x >> 3);
  const int m0 = (nid & 3) * 128, n0 = (nid >> 2) * 128;

  const int lane = t & 63, wid = t >> 6;
  const int wm = (wid >> 1) * 64, wn = (wid & 1) * 64;
  const int fr = lane & 15, fq = lane >> 4;
  // ds_read swizzled 16B-slot: slot = fq ^ (row&3), row&3 == fr&3
  const int rslot = (fq ^ (fr & 3)) * 8;                  // bf16 units

  // staging (2 calls/operand/subtile, 256 thr each): call c covers
  // row = c*64 + (t>>2), dest-slot = t&3; source col16 = (t&3)^((t>>2)&3).
  const int srow = t >> 2;                                 // 0..63
  const int scol = ((t & 3) ^ ((t >> 2) & 3)) * 8;         // bf16 units
  const __hip_bfloat16* Ab = A  + (size_t)(m0 + srow) * KDIM + scol;
  const __hip_bfloat16* Bb = Bm + (size_t)(n0 + srow) * KDIM + scol;

  const f32x4 fz = {0.f, 0.f, 0.f, 0.f};
  f32x4 acc[4][4];
#pragma unroll
  for (int i = 0; i < 4; ++i)
#pragma unroll
    for (int j = 0; j < 4; ++j) acc[i][j] = fz;

#define STG_BIG(tile)                                                   \
  do {                                                                  \
    const int kof = (tile) * 32; const int bb = (tile) & 1;             \
    gload_lds16(Ab + kof,                       lsA[bb] + wid * 512);   \
    gload_lds16(Ab + kof + (size_t)64 * KDIM,   lsA[bb] + 2048 + wid * 512); \
    gload_lds16(Bb + kof,                       lsB[bb] + wid * 512);   \
    gload_lds16(Bb + kof + (size_t)64 * KDIM,   lsB[bb] + 2048 + wid * 512); \
  } while (0)

  STG_BIG(0);
  STG_BIG(1);
#pragma unroll 1
  for (int it = 0; it < 16; ++it) {
    if (it < 15) asm volatile("s_waitcnt vmcnt(4)" ::: "memory");  // tile it landed
    else         asm volatile("s_waitcnt vmcnt(0)" ::: "memory");
    __builtin_amdgcn_sched_barrier(0);
    __builtin_amdgcn_s_barrier();
    __builtin_amdgcn_sched_barrier(0);
    const __hip_bfloat16* lA = lsA[it & 1];
    const __hip_bfloat16* lB = lsB[it & 1];
    short8 af[4], bf[4];
#pragma unroll
    for (int mi = 0; mi < 4; ++mi)
      af[mi] = *(const short8*)(lA + (wm + mi * 16 + fr) * 32 + rslot);
#pragma unroll
    for (int ni = 0; ni < 4; ++ni)
      bf[ni] = *(const short8*)(lB + (wn + ni * 16 + fr) * 32 + rslot);
#pragma unroll
    for (int mi = 0; mi < 4; ++mi)
#pragma unroll
      for (int ni = 0; ni < 4; ++ni)
        acc[mi][ni] = __builtin_amdgcn_mfma_f32_16x16x32_bf16(af[mi], bf[ni], acc[mi][ni], 0, 0, 0);
    __builtin_amdgcn_sched_barrier(0);
    __builtin_amdgcn_s_barrier();       // all reads of buf[it&1] done
    __builtin_amdgcn_sched_barrier(0);
    if (it < 14) STG_BIG(it + 2);       // refill just-read buffer
  }
#undef STG_BIG

#pragma unroll
  for (int mi = 0; mi < 4; ++mi) {
#pragma unroll
    for (int ni = 0; ni < 4; ++ni) {
      const int gn = n0 + wn + ni * 16 + fr;
      const int outer = gn / P56;
      const int ii = gn - outer * P56;
#pragma unroll
      for (int r = 0; r < 4; ++r) {
        const int co = m0 + wm + mi * 16 + fq * 4 + r;
        out[((size_t)outer * NC + co) * P56 + ii] = acc[mi][ni][r] * scale[co] + bias[co];
      }
    }
  }
}

// ---------------------------------------------------------------- fused QKV GEMM: same 128²+swizzle+counted template.
// M=1536 (3x512), N=1568(pad 1664), K=512. grid = 13*12 = 156.
__global__ __launch_bounds__(256) void k_gemm_qkv(
    const __hip_bfloat16* __restrict__ wqb, const __hip_bfloat16* __restrict__ wkb,
    const __hip_bfloat16* __restrict__ wvb, const __hip_bfloat16* __restrict__ xs,
    const float* __restrict__ sq, const float* __restrict__ bq,
    const float* __restrict__ sk, const float* __restrict__ bk,
    const float* __restrict__ sv, const float* __restrict__ bv,
    float* __restrict__ qb, float* __restrict__ kb, float* __restrict__ vb) {
  __shared__ __align__(16) __hip_bfloat16 lsA[2][128 * 32];
  __shared__ __align__(16) __hip_bfloat16 lsB[2][128 * 32];
  const int t = threadIdx.x;
  // bijective XCD swizzle (m204), nwg = 156 (r=4)
  const int nwg = gridDim.x;
  const int orig = blockIdx.x;
  const int q = nwg >> 3, r = nwg & 7;
  const int xcd = orig & 7, pos = orig >> 3;
  const int nid = (xcd < r ? xcd * (q + 1) : r * (q + 1) + (xcd - r) * q) + pos;
  const int mt = nid % 12, nt = nid / 12;   // 12 m-tiles adjacent per n-tile
  const int n0 = nt * 128, m0 = (mt & 3) * 128, sel = mt >> 2;

  const __hip_bfloat16* A = (sel == 0 ? wqb : sel == 1 ? wkb : wvb);
  const float* scale = (sel == 0 ? sq : sel == 1 ? sk : sv);
  const float* bias  = (sel == 0 ? bq : sel == 1 ? bk : bv);
  float* out = (sel == 0 ? qb : sel == 1 ? kb : vb);

  const int lane = t & 63, wid = t >> 6;
  const int wm = (wid >> 1) * 64, wn = (wid & 1) * 64;
  const int fr = lane & 15, fq = lane >> 4;
  const int rslot = (fq ^ (fr & 3)) * 8;
  const int srow = t >> 2;
  const int scol = ((t & 3) ^ ((t >> 2) & 3)) * 8;
  const __hip_bfloat16* Ab = A  + (size_t)(m0 + srow) * KDIM + scol;
  const __hip_bfloat16* Bb = xs + (size_t)(n0 + srow) * KDIM + scol;   // rows < 1664 (padded)

  const f32x4 fz = {0.f, 0.f, 0.f, 0.f};
  f32x4 acc[4][4];
#pragma unroll
  for (int i = 0; i < 4; ++i)
#pragma unroll
    for (int j = 0; j < 4; ++j) acc[i][j] = fz;

#define STG_QKV(tile)                                                   \
  do {                                                                  \
    const int kof = (tile) * 32; const int bb = (tile) & 1;             \
    gload_lds16(Ab + kof,                       lsA[bb] + wid * 512);   \
    gload_lds16(Ab + kof + (size_t)64 * KDIM,   lsA[bb] + 2048 + wid * 512); \
    gload_lds16(Bb + kof,                       lsB[bb] + wid * 512);   \
    gload_lds16(Bb + kof + (size_t)64 * KDIM,   lsB[bb] + 2048 + wid * 512); \
  } while (0)

  STG_QKV(0);
  STG_QKV(1);
#pragma unroll 1
  for (int it = 0; it < 16; ++it) {
    if (it < 15) asm volatile("s_waitcnt vmcnt(4)" ::: "memory");
    else         asm volatile("s_waitcnt vmcnt(0)" ::: "memory");
    __builtin_amdgcn_sched_barrier(0);
    __builtin_amdgcn_s_barrier();
    __builtin_amdgcn_sched_barrier(0);
    const __hip_bfloat16* lA = lsA[it & 1];
    const __hip_bfloat16* lB = lsB[it & 1];
    short8 af[4], bf[4];
#pragma unroll
    for (int mi = 0; mi < 4; ++mi)
      af[mi] = *(const short8*)(lA + (wm + mi * 16 + fr) * 32 + rslot);
#pragma unroll
    for (int ni = 0; ni < 4; ++ni)
      bf[ni] = *(const short8*)(lB + (wn + ni * 16 + fr) * 32 + rslot);
#pragma unroll
    for (int mi = 0; mi < 4; ++mi)
#pragma unroll
      for (int ni = 0; ni < 4; ++ni)
        acc[mi][ni] = __builtin_amdgcn_mfma_f32_16x16x32_bf16(af[mi], bf[ni], acc[mi][ni], 0, 0, 0);
    __builtin_amdgcn_sched_barrier(0);
    __builtin_amdgcn_s_barrier();
    __builtin_amdgcn_sched_barrier(0);
    if (it < 14) STG_QKV(it + 2);
  }
#undef STG_QKV

#pragma unroll
  for (int mi = 0; mi < 4; ++mi) {
#pragma unroll
    for (int ni = 0; ni < 4; ++ni) {
      const int gn = n0 + wn + ni * 16 + fr;
      if (gn >= NTOK) continue;          // pad rows masked here
      const int b = gn / 49, ii = gn - b * 49;
#pragma unroll
      for (int r = 0; r < 4; ++r) {
        const int co = m0 + wm + mi * 16 + fq * 4 + r;
        out[((size_t)b * NC + co) * 49 + ii] = acc[mi][ni][r] * scale[co] + bias[co];
      }
    }
  }
}

// ---------------------------------------------------------------- im2col for grouped 3x3: bloc[g][1568][576] bf16
__global__ __launch_bounds__(256) void k_im2col(
    const float* __restrict__ vb, __hip_bfloat16* __restrict__ bloc) {
  const int g = blockIdx.x, b = blockIdx.y, t = threadIdx.x;
  __shared__ __hip_bfloat16 pad[64][81];   // 9x9 zero-padded 7x7 grid per ci
  for (int i = t; i < 64 * 81; i += 256) pad[i / 81][i % 81] = __float2bfloat16(0.f);
  __syncthreads();
  const float* src = vb + ((size_t)b * NC + g * 64) * 49;
  for (int i = t; i < 64 * 49; i += 256) {
    const int ci = i / 49, n = i - ci * 49;
    const int oh = n / 7, ow = n - oh * 7;
    pad[ci][(oh + 1) * 9 + (ow + 1)] = __float2bfloat16(src[i]);
  }
  __syncthreads();
  __hip_bfloat16* dst = bloc + ((size_t)g * NTOK + (size_t)b * 49) * KLOC;
  for (int i = t; i < 49 * KLOC; i += 256) {
    const int n = i / KLOC, k = i - n * KLOC;
    const int ci = k / 9, tap = k - ci * 9;
    const int kh = tap / 3, kw = tap - kh * 3;
    const int oh = n / 7, ow = n - oh * 7;
    dst[i] = pad[ci][(oh + kh) * 9 + (ow + kw)];
  }
}

// ---------------------------------------------------------------- v_local GEMM: per group, M=64, K=576, N=1568
__global__ __launch_bounds__(256) void k_vloc_gemm(
    const __hip_bfloat16* __restrict__ lwb,   // [512][576] bf16
    const __hip_bfloat16* __restrict__ bloc,  // [8][1568][576] bf16
    const float* __restrict__ lbias, const float* __restrict__ sl,
    const float* __restrict__ bl, float* __restrict__ vloc) {
  __shared__ __align__(16) unsigned short la[64][40];
  __shared__ __align__(16) unsigned short lb[128][40];
  const int t = threadIdx.x;
  const int g = blockIdx.y;
  const int n0 = blockIdx.x * 128;
  const int lane = t & 63, wid = t >> 6;
  const int wm = (wid >> 1) * 32, wn = (wid & 1) * 64;
  const int fr = lane & 15, fq = lane >> 4, kg = fq * 8;

  const f32x4 fz = {0.f, 0.f, 0.f, 0.f};
  f32x4 acc[2][4];
#pragma unroll
  for (int i = 0; i < 2; ++i)
#pragma unroll
    for (int j = 0; j < 4; ++j) acc[i][j] = fz;

  const int r0 = t >> 2, kk = (t & 3) * 8;
  const short8 z8 = {0, 0, 0, 0, 0, 0, 0, 0};
  const __hip_bfloat16* As = lwb + (size_t)g * 64 * KLOC;
  const __hip_bfloat16* Bs = bloc + (size_t)g * NTOK * KLOC;

  for (int k0 = 0; k0 < KLOC; k0 += 32) {
    __syncthreads();
    *(short8*)(&la[r0][kk]) = *(const short8*)(As + (size_t)r0 * KLOC + k0 + kk);
#pragma unroll
    for (int rr = 0; rr < 128; rr += 64) {
      const int row = r0 + rr;
      const int gn = n0 + row;
      short8 vb8 = z8;
      if (gn < NTOK) vb8 = *(const short8*)(Bs + (size_t)gn * KLOC + k0 + kk);
      *(short8*)(&lb[row][kk]) = vb8;
    }
    __syncthreads();
    short8 af[2], bfv[4];
#pragma unroll
    for (int mi = 0; mi < 2; ++mi) af[mi] = *(const short8*)(&la[wm + mi * 16 + fr][kg]);
#pragma unroll
    for (int ni = 0; ni < 4; ++ni) bfv[ni] = *(const short8*)(&lb[wn + ni * 16 + fr][kg]);
#pragma unroll
    for (int mi = 0; mi < 2; ++mi)
#pragma unroll
      for (int ni = 0; ni < 4; ++ni)
        acc[mi][ni] = __builtin_amdgcn_mfma_f32_16x16x32_bf16(af[mi], bfv[ni], acc[mi][ni], 0, 0, 0);
  }

#pragma unroll
  for (int mi = 0; mi < 2; ++mi) {
#pragma unroll
    for (int ni = 0; ni < 4; ++ni) {
      const int gn = n0 + wn + ni * 16 + fr;
      if (gn >= NTOK) continue;
      const int b = gn / 49, n = gn - b * 49;
#pragma unroll
      for (int r = 0; r < 4; ++r) {
        const int oc = g * 64 + wm + mi * 16 + fq * 4 + r;
        const float sc = sl[oc];
        vloc[((size_t)b * NC + oc) * 49 + n] = acc[mi][ni][r] * sc + lbias[oc] * sc + bl[oc];
      }
    }
  }
}

// ---------------------------------------------------------------- A1: normalized QK^T * ls + bias -> S[b][h][49][49]
__global__ __launch_bounds__(256) void k_attn1(
    const float* __restrict__ qb, const float* __restrict__ kb,
    const float* __restrict__ lsc, const float* __restrict__ ab, const int* __restrict__ bidx,
    float* __restrict__ Sbuf) {
  const int h = blockIdx.x, b = blockIdx.y, t = threadIdx.x;
  __shared__ float qt[64 * 49], kt[64 * 49], nq[49], abl[49];
  const float* qs = qb + ((size_t)b * NC + h * 64) * 49;
  const float* ks = kb + ((size_t)b * NC + h * 64) * 49;
  for (int i = t; i < 64 * 49; i += 256) { qt[i] = qs[i]; kt[i] = ks[i]; }
  if (t < 49) abl[t] = ab[h * 49 + t];
  __syncthreads();
  if (t < 49) {                       // q norm per token (over d)
    float s = 0.f;
    for (int d = 0; d < 64; ++d) { float v = qt[d * 49 + t]; s += v * v; }
    nq[t] = fmaxf(sqrtf(s), 1e-12f);
  } else if (t >= 64 && t < 128) {    // k norm per channel (over tokens), normalize in place
    const int d = t - 64;
    float s = 0.f;
    for (int m = 0; m < 49; ++m) { float v = kt[d * 49 + m]; s += v * v; }
    const float inv = 1.f / fmaxf(sqrtf(s), 1e-12f);
    for (int m = 0; m < 49; ++m) kt[d * 49 + m] *= inv;
  }
  __syncthreads();
  const float ls = expf(fminf(lsc[h], logf(100.f)));
  for (int idx = t; idx < 49 * 49; idx += 256) {
    const int n = idx / 49, m = idx - n * 49;
    float acc = 0.f;
    for (int d = 0; d < 64; ++d) acc += qt[d * 49 + n] * kt[d * 49 + m];
    Sbuf[(((size_t)b * NHD + h) * 49 + n) * 49 + m] = acc / nq[n] * ls + abl[bidx[idx]];
  }
}

// ---------------------------------------------------------------- A2: th1 -> softmax -> th2 -> PV + vloc -> y7[b][n][c]
__global__ __launch_bounds__(256) void k_attn2(
    const float* __restrict__ Sbuf, const float* __restrict__ th1, const float* __restrict__ th2,
    const float* __restrict__ vb, const float* __restrict__ vloc, float* __restrict__ y7) {
  const int n = blockIdx.x, b = blockIdx.y, t = threadIdx.x;
  __shared__ float sS[8][49], sP[8][49], sQ[8][49];
  __shared__ float t1[64], t2[64], rsuminv[8];
  if (t < 64) { t1[t] = th1[t]; t2[t] = th2[t]; }
  for (int i = t; i < 392; i += 256) {
    const int j = i / 49, m = i - j * 49;
    sS[j][m] = Sbuf[(((size_t)b * NHD + j) * 49 + n) * 49 + m];
  }
  __syncthreads();
  for (int i = t; i < 392; i += 256) {
    const int j = i / 49, m = i - j * 49;
    float a = 0.f;
#pragma unroll
    for (int jj = 0; jj < 8; ++jj) a += t1[j * 8 + jj] * sS[jj][m];
    sP[j][m] = a;
  }
  __syncthreads();
  if (t < 8) {
    float mx = -1e30f;
    for (int m = 0; m < 49; ++m) mx = fmaxf(mx, sP[t][m]);
    float s = 0.f;
    for (int m = 0; m < 49; ++m) { float e = expf(sP[t][m] - mx); sP[t][m] = e; s += e; }
    rsuminv[t] = 1.f / s;
  }
  __syncthreads();
  for (int i = t; i < 392; i += 256) {
    const int j = i / 49, m = i - j * 49;
    float a = 0.f;
#pragma unroll
    for (int jj = 0; jj < 8; ++jj) a += t2[j * 8 + jj] * (sP[jj][m] * rsuminv[jj]);
    sQ[j][m] = a;
  }
  __syncthreads();
  for (int c = t; c < NC; c += 256) {
    const int hh = c >> 6;
    const float* vp = vb + ((size_t)b * NC + c) * 49;
    float a = 0.f;
    for (int m = 0; m < 49; ++m) a += sQ[hh][m] * vp[m];
    a += vloc[((size_t)b * NC + c) * 49 + n];
    y7[((size_t)b * 49 + n) * NC + c] = a;
  }
}

// ---------------------------------------------------------------- bilinear 7->56 + hardswish -> h[100352][512] bf16 (vectorized stores)
__global__ __launch_bounds__(256) void k_resize(const float* __restrict__ y7,
                                                __hip_bfloat16* __restrict__ h) {
  const int y = blockIdx.x, b = blockIdx.y, t = threadIdx.x;
  __shared__ float L[2][7][512];
  float sy = (y - 3.5f) * 0.125f;
  sy = fminf(fmaxf(sy, 0.f), 6.f);
  const int iy0 = min((int)floorf(sy), 5);
  const float wy = sy - (float)iy0;
  const float* src = y7 + ((size_t)b * 49 + iy0 * 7) * NC;
  float* Lf = &L[0][0][0];
  for (int i = t; i < 2 * 7 * 512; i += 256) Lf[i] = src[i];
  __syncthreads();
  const size_t outb = ((size_t)b * P56 + (size_t)y * 56) * NC;
  const int c0 = t * 2;                 // 256 threads x 2 ch = 512
  for (int x = 0; x < 56; ++x) {
    float sx = (x - 3.5f) * 0.125f;
    sx = fminf(fmaxf(sx, 0.f), 6.f);
    const int ix0 = min((int)floorf(sx), 5);
    const float wx = sx - (float)ix0;
    const float w00 = (1.f - wy) * (1.f - wx), w01 = (1.f - wy) * wx;
    const float w10 = wy * (1.f - wx),         w11 = wy * wx;
    float hs[2];
#pragma unroll
    for (int j = 0; j < 2; ++j) {
      const int c = c0 + j;
      const float v = w00 * L[0][ix0][c] + w01 * L[0][ix0 + 1][c]
                    + w10 * L[1][ix0][c] + w11 * L[1][ix0 + 1][c];
      hs[j] = v * fminf(fmaxf(v + 3.f, 0.f), 6.f) * (1.f / 6.f);
    }
    __hip_bfloat162 p;
    p.x = __float2bfloat16(hs[0]);
    p.y = __float2bfloat16(hs[1]);
    *(__hip_bfloat162*)(&h[outb + (size_t)x * NC + c0]) = p;
  }
}

// ----------------------------------------------------------------
extern "C" void kernel_launch(void* const* d_in, const int* in_sizes, int n_in,
                              void* d_out, int out_size, void* d_ws, size_t ws_size,
                              hipStream_t stream) {
  (void)in_sizes; (void)n_in; (void)out_size; (void)ws_size;
  const float* x     = (const float*)d_in[0];
  const float* dw_w  = (const float*)d_in[1];
  const float* bn0_s = (const float*)d_in[2];
  const float* bn0_b = (const float*)d_in[3];
  const float* wq    = (const float*)d_in[4];
  const float* bnq_s = (const float*)d_in[5];
  const float* bnq_b = (const float*)d_in[6];
  const float* wk    = (const float*)d_in[7];
  const float* bnk_s = (const float*)d_in[8];
  const float* bnk_b = (const float*)d_in[9];
  const float* wv    = (const float*)d_in[10];
  const float* bnv_s = (const float*)d_in[11];
  const float* bnv_b = (const float*)d_in[12];
  const float* loc_w = (const float*)d_in[13];
  const float* loc_b = (const float*)d_in[14];
  const float* bnl_s = (const float*)d_in[15];
  const float* bnl_b = (const float*)d_in[16];
  const float* th1   = (const float*)d_in[17];
  const float* th2   = (const float*)d_in[18];
  const float* lsc   = (const float*)d_in[19];
  const float* ab    = (const float*)d_in[20];
  const float* wo    = (const float*)d_in[21];
  const float* bno_s = (const float*)d_in[22];
  const float* bno_b = (const float*)d_in[23];
  const int*   bidx  = (const int*)d_in[24];

  char* w = (char*)d_ws;
  auto alloc = [&](size_t bytes) {
    char* p = w;
    w += (bytes + 255) & ~(size_t)255;
    return p;
  };
  __hip_bfloat16* h_buf = (__hip_bfloat16*)alloc((size_t)NBIG * NC * 2);
  __hip_bfloat16* wq_b  = (__hip_bfloat16*)alloc((size_t)NC * NC * 2);
  __hip_bfloat16* wk_b  = (__hip_bfloat16*)alloc((size_t)NC * NC * 2);
  __hip_bfloat16* wv_b  = (__hip_bfloat16*)alloc((size_t)NC * NC * 2);
  __hip_bfloat16* wo_b  = (__hip_bfloat16*)alloc((size_t)NC * NC * 2);
  __hip_bfloat16* lw_b  = (__hip_bfloat16*)alloc((size_t)NC * KLOC * 2);
  __hip_bfloat16* xs    = (__hip_bfloat16*)alloc((size_t)NTOKP * NC * 2);  // padded rows
  float* qb   = (float*)alloc((size_t)NB * NC * 49 * 4);
  float* kb   = (float*)alloc((size_t)NB * NC * 49 * 4);
  float* vb   = (float*)alloc((size_t)NB * NC * 49 * 4);
  float* vloc = (float*)alloc((size_t)NB * NC * 49 * 4);
  float* y7   = (float*)alloc((size_t)NB * 49 * NC * 4);
  float* Sb   = (float*)alloc((size_t)NB * NHD * 49 * 49 * 4);
  // bloc aliases h_buf: bloc dies (after k_vloc_gemm) before h_buf is written (k_resize)
  __hip_bfloat16* bloc = (__hip_bfloat16*)h_buf;   // 14.5 MB << 103 MB

  k_cvt<<<dim3(128, 5), 256, 0, stream>>>(wq, wk, wv, wo, loc_w,
                                          wq_b, wk_b, wv_b, wo_b, lw_b);
  k_stride<<<dim3(NC, NB), 64, 0, stream>>>(x, dw_w, bn0_s, bn0_b, xs);
  k_gemm_qkv<<<dim3(13 * 12), 256, 0, stream>>>(wq_b, wk_b, wv_b, xs,
                                                bnq_s, bnq_b, bnk_s, bnk_b, bnv_s, bnv_b,
                                                qb, kb, vb);
  k_im2col<<<dim3(NHD, NB), 256, 0, stream>>>(vb, bloc);
  k_vloc_gemm<<<dim3(13, NHD), 256, 0, stream>>>(lw_b, bloc, loc_b, bnl_s, bnl_b, vloc);
  k_attn1<<<dim3(NHD, NB), 256, 0, stream>>>(qb, kb, lsc, ab, bidx, Sb);
  k_attn2<<<dim3(49, NB), 256, 0, stream>>>(Sb, th1, th2, vb, vloc, y7);
  k_resize<<<dim3(RES, NB), 256, 0, stream>>>(y7, h_buf);
  k_gemm_big<<<dim3(4 * 784), 256, 0, stream>>>(wo_b, h_buf, bno_s, bno_b, (float*)d_out);
}

// Round 9
// 278.409 us; speedup vs baseline: 1.0066x; 1.0066x over previous
//
#include <hip/hip_runtime.h>
#include <hip/hip_bf16.h>
#include <stdint.h>

typedef short short8 __attribute__((ext_vector_type(8)));
typedef float f32x4 __attribute__((ext_vector_type(4)));

#define NB    32
#define NC    512
#define NHD   8
#define HDD   64
#define N7    49
#define RES   56
#define P56   3136
#define NTOK  1568     // 32*49
#define NTOKP 1664     // padded to 13*128 for unguarded staging
#define NBIG  100352   // 32*3136
#define KDIM  512
#define KLOC  576      // 64ci * 9taps

// async global->LDS, 16B per lane; LDS dest is wave-uniform base + lane*16
__device__ __forceinline__ void gload_lds16(const __hip_bfloat16* g, __hip_bfloat16* l) {
  __builtin_amdgcn_global_load_lds(
      (const __attribute__((address_space(1))) void*)g,
      (__attribute__((address_space(3))) void*)l, 16, 0, 0);
}

// ---------------------------------------------------------------- K0: fp32 -> bf16 weight convert (4x 512x512 + loc_w 512x576)
__global__ __launch_bounds__(256) void k_cvt(
    const float* __restrict__ s0, const float* __restrict__ s1,
    const float* __restrict__ s2, const float* __restrict__ s3,
    const float* __restrict__ s4,
    __hip_bfloat16* __restrict__ d0, __hip_bfloat16* __restrict__ d1,
    __hip_bfloat16* __restrict__ d2, __hip_bfloat16* __restrict__ d3,
    __hip_bfloat16* __restrict__ d4) {
  const float* s; __hip_bfloat16* d; int n = NC * NC;
  switch (blockIdx.y) {
    case 0: s = s0; d = d0; break;
    case 1: s = s1; d = d1; break;
    case 2: s = s2; d = d2; break;
    case 3: s = s3; d = d3; break;
    default: s = s4; d = d4; n = NC * KLOC; break;
  }
  for (int i = blockIdx.x * blockDim.x + threadIdx.x; i < n; i += gridDim.x * blockDim.x)
    d[i] = __float2bfloat16(s[i]);
}

// ---------------------------------------------------------------- K1: depthwise 3x3 stride-8 + BN0 -> xs[1568][512] bf16
__global__ __launch_bounds__(64) void k_stride(
    const float* __restrict__ x, const float* __restrict__ dw,
    const float* __restrict__ s0, const float* __restrict__ b0,
    __hip_bfloat16* __restrict__ xs) {
  const int ci = blockIdx.x, b = blockIdx.y, t = threadIdx.x;
  __shared__ float rows[21][56];
  const float* xp = x + ((size_t)(b * NC + ci)) * RES * RES;
  for (int r = t; r < 21 * 56; r += 64) {
    int rr = r / 56, cc = r - rr * 56;
    int oh = rr / 3, kh = rr - oh * 3;
    int ih = oh * 8 + kh - 1;
    rows[rr][cc] = (ih >= 0) ? xp[ih * 56 + cc] : 0.f;
  }
  float w[9];
#pragma unroll
  for (int j = 0; j < 9; ++j) w[j] = dw[ci * 9 + j];
  const float sc = s0[ci], bi = b0[ci];
  __syncthreads();
  if (t < 49) {
    const int oh = t / 7, ow = t - oh * 7;
    float acc = 0.f;
#pragma unroll
    for (int kh = 0; kh < 3; ++kh)
#pragma unroll
      for (int kw = 0; kw < 3; ++kw) {
        int col = ow * 8 + kw - 1;
        float v = (col >= 0) ? rows[oh * 3 + kh][col] : 0.f;
        acc += v * w[kh * 3 + kw];
      }
    xs[(size_t)(b * 49 + t) * NC + ci] = __float2bfloat16(acc * sc + bi);
  }
}

// ---------------------------------------------------------------- BIG GEMM: 128x128 tile, BK=32, 2-deep counted vmcnt,
// CORRECTED bijective swizzle (8-lane groups -> 8 distinct 16B slots),
// 32 KB LDS -> ~4 blocks/CU. M=512, N=100352, K=512. grid = 3136 x 256.
__global__ __launch_bounds__(256) void k_gemm_big(
    const __hip_bfloat16* __restrict__ A,    // [512][512] bf16
    const __hip_bfloat16* __restrict__ Bm,   // [100352][512] bf16
    const float* __restrict__ scale, const float* __restrict__ bias,
    float* __restrict__ out) {
  __shared__ __align__(16) __hip_bfloat16 lsA[2][128 * 32];
  __shared__ __align__(16) __hip_bfloat16 lsB[2][128 * 32];
  const int t = threadIdx.x;
  // XCD swizzle: 3136 % 8 == 0 -> chunked bijective; 4 m-tiles per B panel adjacent
  const int cpx = gridDim.x >> 3;
  const int nid = (blockIdx.x & 7) * cpx + (blockIdx.x >> 3);
  const int m0 = (nid & 3) * 128, n0 = (nid >> 2) * 128;

  const int lane = t & 63, wid = t >> 6;
  const int wm = (wid >> 1) * 64, wn = (wid & 1) * 64;
  const int fr = lane & 15, fq = lane >> 4;
  // ds_read slot: fq ^ ((row>>1)&3). Lanes 0-7 then hit 16B-slot indices
  // {0,4,1,5,2,6,3,7} within the 128B line -> conflict-free. (R7's fr&3 was not.)
  const int rslot = (fq ^ ((fr >> 1) & 3)) * 8;            // bf16 units

  // staging inverse: row = t>>2, dest slot = t&3, source col16 = (t&3)^((row>>1)&3)
  const int srow = t >> 2;                                 // 0..63
  const int scol = ((t & 3) ^ ((t >> 3) & 3)) * 8;         // bf16 units
  const __hip_bfloat16* Ab = A  + (size_t)(m0 + srow) * KDIM + scol;
  const __hip_bfloat16* Bb = Bm + (size_t)(n0 + srow) * KDIM + scol;

  const f32x4 fz = {0.f, 0.f, 0.f, 0.f};
  f32x4 acc[4][4];
#pragma unroll
  for (int i = 0; i < 4; ++i)
#pragma unroll
    for (int j = 0; j < 4; ++j) acc[i][j] = fz;

#define STG_BIG(tile)                                                   \
  do {                                                                  \
    const int kof = (tile) * 32; const int bb = (tile) & 1;             \
    gload_lds16(Ab + kof,                       lsA[bb] + wid * 512);   \
    gload_lds16(Ab + kof + (size_t)64 * KDIM,   lsA[bb] + 2048 + wid * 512); \
    gload_lds16(Bb + kof,                       lsB[bb] + wid * 512);   \
    gload_lds16(Bb + kof + (size_t)64 * KDIM,   lsB[bb] + 2048 + wid * 512); \
  } while (0)

  STG_BIG(0);
  STG_BIG(1);
#pragma unroll 1
  for (int it = 0; it < 16; ++it) {
    if (it < 15) asm volatile("s_waitcnt vmcnt(4)" ::: "memory");  // tile it landed
    else         asm volatile("s_waitcnt vmcnt(0)" ::: "memory");
    __builtin_amdgcn_sched_barrier(0);
    __builtin_amdgcn_s_barrier();
    __builtin_amdgcn_sched_barrier(0);
    const __hip_bfloat16* lA = lsA[it & 1];
    const __hip_bfloat16* lB = lsB[it & 1];
    short8 af[4], bf[4];
#pragma unroll
    for (int mi = 0; mi < 4; ++mi)
      af[mi] = *(const short8*)(lA + (wm + mi * 16 + fr) * 32 + rslot);
#pragma unroll
    for (int ni = 0; ni < 4; ++ni)
      bf[ni] = *(const short8*)(lB + (wn + ni * 16 + fr) * 32 + rslot);
#pragma unroll
    for (int mi = 0; mi < 4; ++mi)
#pragma unroll
      for (int ni = 0; ni < 4; ++ni)
        acc[mi][ni] = __builtin_amdgcn_mfma_f32_16x16x32_bf16(af[mi], bf[ni], acc[mi][ni], 0, 0, 0);
    __builtin_amdgcn_sched_barrier(0);
    __builtin_amdgcn_s_barrier();       // all reads of buf[it&1] done
    __builtin_amdgcn_sched_barrier(0);
    if (it < 14) STG_BIG(it + 2);       // refill just-read buffer
  }
#undef STG_BIG

#pragma unroll
  for (int mi = 0; mi < 4; ++mi) {
#pragma unroll
    for (int ni = 0; ni < 4; ++ni) {
      const int gn = n0 + wn + ni * 16 + fr;
      const int outer = gn / P56;
      const int ii = gn - outer * P56;
#pragma unroll
      for (int r = 0; r < 4; ++r) {
        const int co = m0 + wm + mi * 16 + fq * 4 + r;
        out[((size_t)outer * NC + co) * P56 + ii] = acc[mi][ni][r] * scale[co] + bias[co];
      }
    }
  }
}

// ---------------------------------------------------------------- fused QKV GEMM: same corrected template.
// M=1536 (3x512), N=1568(pad 1664), K=512. grid = 13*12 = 156.
__global__ __launch_bounds__(256) void k_gemm_qkv(
    const __hip_bfloat16* __restrict__ wqb, const __hip_bfloat16* __restrict__ wkb,
    const __hip_bfloat16* __restrict__ wvb, const __hip_bfloat16* __restrict__ xs,
    const float* __restrict__ sq, const float* __restrict__ bq,
    const float* __restrict__ sk, const float* __restrict__ bk,
    const float* __restrict__ sv, const float* __restrict__ bv,
    float* __restrict__ qb, float* __restrict__ kb, float* __restrict__ vb) {
  __shared__ __align__(16) __hip_bfloat16 lsA[2][128 * 32];
  __shared__ __align__(16) __hip_bfloat16 lsB[2][128 * 32];
  const int t = threadIdx.x;
  // bijective XCD swizzle (m204), nwg = 156 (r=4)
  const int nwg = gridDim.x;
  const int orig = blockIdx.x;
  const int q = nwg >> 3, r = nwg & 7;
  const int xcd = orig & 7, pos = orig >> 3;
  const int nid = (xcd < r ? xcd * (q + 1) : r * (q + 1) + (xcd - r) * q) + pos;
  const int mt = nid % 12, nt = nid / 12;   // 12 m-tiles adjacent per n-tile
  const int n0 = nt * 128, m0 = (mt & 3) * 128, sel = mt >> 2;

  const __hip_bfloat16* A = (sel == 0 ? wqb : sel == 1 ? wkb : wvb);
  const float* scale = (sel == 0 ? sq : sel == 1 ? sk : sv);
  const float* bias  = (sel == 0 ? bq : sel == 1 ? bk : bv);
  float* out = (sel == 0 ? qb : sel == 1 ? kb : vb);

  const int lane = t & 63, wid = t >> 6;
  const int wm = (wid >> 1) * 64, wn = (wid & 1) * 64;
  const int fr = lane & 15, fq = lane >> 4;
  const int rslot = (fq ^ ((fr >> 1) & 3)) * 8;
  const int srow = t >> 2;
  const int scol = ((t & 3) ^ ((t >> 3) & 3)) * 8;
  const __hip_bfloat16* Ab = A  + (size_t)(m0 + srow) * KDIM + scol;
  const __hip_bfloat16* Bb = xs + (size_t)(n0 + srow) * KDIM + scol;   // rows < 1664 (padded)

  const f32x4 fz = {0.f, 0.f, 0.f, 0.f};
  f32x4 acc[4][4];
#pragma unroll
  for (int i = 0; i < 4; ++i)
#pragma unroll
    for (int j = 0; j < 4; ++j) acc[i][j] = fz;

#define STG_QKV(tile)                                                   \
  do {                                                                  \
    const int kof = (tile) * 32; const int bb = (tile) & 1;             \
    gload_lds16(Ab + kof,                       lsA[bb] + wid * 512);   \
    gload_lds16(Ab + kof + (size_t)64 * KDIM,   lsA[bb] + 2048 + wid * 512); \
    gload_lds16(Bb + kof,                       lsB[bb] + wid * 512);   \
    gload_lds16(Bb + kof + (size_t)64 * KDIM,   lsB[bb] + 2048 + wid * 512); \
  } while (0)

  STG_QKV(0);
  STG_QKV(1);
#pragma unroll 1
  for (int it = 0; it < 16; ++it) {
    if (it < 15) asm volatile("s_waitcnt vmcnt(4)" ::: "memory");
    else         asm volatile("s_waitcnt vmcnt(0)" ::: "memory");
    __builtin_amdgcn_sched_barrier(0);
    __builtin_amdgcn_s_barrier();
    __builtin_amdgcn_sched_barrier(0);
    const __hip_bfloat16* lA = lsA[it & 1];
    const __hip_bfloat16* lB = lsB[it & 1];
    short8 af[4], bf[4];
#pragma unroll
    for (int mi = 0; mi < 4; ++mi)
      af[mi] = *(const short8*)(lA + (wm + mi * 16 + fr) * 32 + rslot);
#pragma unroll
    for (int ni = 0; ni < 4; ++ni)
      bf[ni] = *(const short8*)(lB + (wn + ni * 16 + fr) * 32 + rslot);
#pragma unroll
    for (int mi = 0; mi < 4; ++mi)
#pragma unroll
      for (int ni = 0; ni < 4; ++ni)
        acc[mi][ni] = __builtin_amdgcn_mfma_f32_16x16x32_bf16(af[mi], bf[ni], acc[mi][ni], 0, 0, 0);
    __builtin_amdgcn_sched_barrier(0);
    __builtin_amdgcn_s_barrier();
    __builtin_amdgcn_sched_barrier(0);
    if (it < 14) STG_QKV(it + 2);
  }
#undef STG_QKV

#pragma unroll
  for (int mi = 0; mi < 4; ++mi) {
#pragma unroll
    for (int ni = 0; ni < 4; ++ni) {
      const int gn = n0 + wn + ni * 16 + fr;
      if (gn >= NTOK) continue;          // pad rows masked here
      const int b = gn / 49, ii = gn - b * 49;
#pragma unroll
      for (int r = 0; r < 4; ++r) {
        const int co = m0 + wm + mi * 16 + fq * 4 + r;
        out[((size_t)b * NC + co) * 49 + ii] = acc[mi][ni][r] * scale[co] + bias[co];
      }
    }
  }
}

// ---------------------------------------------------------------- im2col for grouped 3x3: bloc[g][1568][576] bf16
__global__ __launch_bounds__(256) void k_im2col(
    const float* __restrict__ vb, __hip_bfloat16* __restrict__ bloc) {
  const int g = blockIdx.x, b = blockIdx.y, t = threadIdx.x;
  __shared__ __hip_bfloat16 pad[64][81];   // 9x9 zero-padded 7x7 grid per ci
  for (int i = t; i < 64 * 81; i += 256) pad[i / 81][i % 81] = __float2bfloat16(0.f);
  __syncthreads();
  const float* src = vb + ((size_t)b * NC + g * 64) * 49;
  for (int i = t; i < 64 * 49; i += 256) {
    const int ci = i / 49, n = i - ci * 49;
    const int oh = n / 7, ow = n - oh * 7;
    pad[ci][(oh + 1) * 9 + (ow + 1)] = __float2bfloat16(src[i]);
  }
  __syncthreads();
  __hip_bfloat16* dst = bloc + ((size_t)g * NTOK + (size_t)b * 49) * KLOC;
  for (int i = t; i < 49 * KLOC; i += 256) {
    const int n = i / KLOC, k = i - n * KLOC;
    const int ci = k / 9, tap = k - ci * 9;
    const int kh = tap / 3, kw = tap - kh * 3;
    const int oh = n / 7, ow = n - oh * 7;
    dst[i] = pad[ci][(oh + kh) * 9 + (ow + kw)];
  }
}

// ---------------------------------------------------------------- v_local GEMM: per group, M=64, K=576, N=1568
__global__ __launch_bounds__(256) void k_vloc_gemm(
    const __hip_bfloat16* __restrict__ lwb,   // [512][576] bf16
    const __hip_bfloat16* __restrict__ bloc,  // [8][1568][576] bf16
    const float* __restrict__ lbias, const float* __restrict__ sl,
    const float* __restrict__ bl, float* __restrict__ vloc) {
  __shared__ __align__(16) unsigned short la[64][40];
  __shared__ __align__(16) unsigned short lb[128][40];
  const int t = threadIdx.x;
  const int g = blockIdx.y;
  const int n0 = blockIdx.x * 128;
  const int lane = t & 63, wid = t >> 6;
  const int wm = (wid >> 1) * 32, wn = (wid & 1) * 64;
  const int fr = lane & 15, fq = lane >> 4, kg = fq * 8;

  const f32x4 fz = {0.f, 0.f, 0.f, 0.f};
  f32x4 acc[2][4];
#pragma unroll
  for (int i = 0; i < 2; ++i)
#pragma unroll
    for (int j = 0; j < 4; ++j) acc[i][j] = fz;

  const int r0 = t >> 2, kk = (t & 3) * 8;
  const short8 z8 = {0, 0, 0, 0, 0, 0, 0, 0};
  const __hip_bfloat16* As = lwb + (size_t)g * 64 * KLOC;
  const __hip_bfloat16* Bs = bloc + (size_t)g * NTOK * KLOC;

  for (int k0 = 0; k0 < KLOC; k0 += 32) {
    __syncthreads();
    *(short8*)(&la[r0][kk]) = *(const short8*)(As + (size_t)r0 * KLOC + k0 + kk);
#pragma unroll
    for (int rr = 0; rr < 128; rr += 64) {
      const int row = r0 + rr;
      const int gn = n0 + row;
      short8 vb8 = z8;
      if (gn < NTOK) vb8 = *(const short8*)(Bs + (size_t)gn * KLOC + k0 + kk);
      *(short8*)(&lb[row][kk]) = vb8;
    }
    __syncthreads();
    short8 af[2], bfv[4];
#pragma unroll
    for (int mi = 0; mi < 2; ++mi) af[mi] = *(const short8*)(&la[wm + mi * 16 + fr][kg]);
#pragma unroll
    for (int ni = 0; ni < 4; ++ni) bfv[ni] = *(const short8*)(&lb[wn + ni * 16 + fr][kg]);
#pragma unroll
    for (int mi = 0; mi < 2; ++mi)
#pragma unroll
      for (int ni = 0; ni < 4; ++ni)
        acc[mi][ni] = __builtin_amdgcn_mfma_f32_16x16x32_bf16(af[mi], bfv[ni], acc[mi][ni], 0, 0, 0);
  }

#pragma unroll
  for (int mi = 0; mi < 2; ++mi) {
#pragma unroll
    for (int ni = 0; ni < 4; ++ni) {
      const int gn = n0 + wn + ni * 16 + fr;
      if (gn >= NTOK) continue;
      const int b = gn / 49, n = gn - b * 49;
#pragma unroll
      for (int r = 0; r < 4; ++r) {
        const int oc = g * 64 + wm + mi * 16 + fq * 4 + r;
        const float sc = sl[oc];
        vloc[((size_t)b * NC + oc) * 49 + n] = acc[mi][ni][r] * sc + lbias[oc] * sc + bl[oc];
      }
    }
  }
}

// ---------------------------------------------------------------- A1: normalized QK^T * ls + bias -> S[b][h][49][49]
__global__ __launch_bounds__(256) void k_attn1(
    const float* __restrict__ qb, const float* __restrict__ kb,
    const float* __restrict__ lsc, const float* __restrict__ ab, const int* __restrict__ bidx,
    float* __restrict__ Sbuf) {
  const int h = blockIdx.x, b = blockIdx.y, t = threadIdx.x;
  __shared__ float qt[64 * 49], kt[64 * 49], nq[49], abl[49];
  const float* qs = qb + ((size_t)b * NC + h * 64) * 49;
  const float* ks = kb + ((size_t)b * NC + h * 64) * 49;
  for (int i = t; i < 64 * 49; i += 256) { qt[i] = qs[i]; kt[i] = ks[i]; }
  if (t < 49) abl[t] = ab[h * 49 + t];
  __syncthreads();
  if (t < 49) {                       // q norm per token (over d)
    float s = 0.f;
    for (int d = 0; d < 64; ++d) { float v = qt[d * 49 + t]; s += v * v; }
    nq[t] = fmaxf(sqrtf(s), 1e-12f);
  } else if (t >= 64 && t < 128) {    // k norm per channel (over tokens), normalize in place
    const int d = t - 64;
    float s = 0.f;
    for (int m = 0; m < 49; ++m) { float v = kt[d * 49 + m]; s += v * v; }
    const float inv = 1.f / fmaxf(sqrtf(s), 1e-12f);
    for (int m = 0; m < 49; ++m) kt[d * 49 + m] *= inv;
  }
  __syncthreads();
  const float ls = expf(fminf(lsc[h], logf(100.f)));
  for (int idx = t; idx < 49 * 49; idx += 256) {
    const int n = idx / 49, m = idx - n * 49;
    float acc = 0.f;
    for (int d = 0; d < 64; ++d) acc += qt[d * 49 + n] * kt[d * 49 + m];
    Sbuf[(((size_t)b * NHD + h) * 49 + n) * 49 + m] = acc / nq[n] * ls + abl[bidx[idx]];
  }
}

// ---------------------------------------------------------------- A2: th1 -> softmax -> th2 -> PV + vloc -> y7[b][n][c]
__global__ __launch_bounds__(256) void k_attn2(
    const float* __restrict__ Sbuf, const float* __restrict__ th1, const float* __restrict__ th2,
    const float* __restrict__ vb, const float* __restrict__ vloc, float* __restrict__ y7) {
  const int n = blockIdx.x, b = blockIdx.y, t = threadIdx.x;
  __shared__ float sS[8][49], sP[8][49], sQ[8][49];
  __shared__ float t1[64], t2[64], rsuminv[8];
  if (t < 64) { t1[t] = th1[t]; t2[t] = th2[t]; }
  for (int i = t; i < 392; i += 256) {
    const int j = i / 49, m = i - j * 49;
    sS[j][m] = Sbuf[(((size_t)b * NHD + j) * 49 + n) * 49 + m];
  }
  __syncthreads();
  for (int i = t; i < 392; i += 256) {
    const int j = i / 49, m = i - j * 49;
    float a = 0.f;
#pragma unroll
    for (int jj = 0; jj < 8; ++jj) a += t1[j * 8 + jj] * sS[jj][m];
    sP[j][m] = a;
  }
  __syncthreads();
  if (t < 8) {
    float mx = -1e30f;
    for (int m = 0; m < 49; ++m) mx = fmaxf(mx, sP[t][m]);
    float s = 0.f;
    for (int m = 0; m < 49; ++m) { float e = expf(sP[t][m] - mx); sP[t][m] = e; s += e; }
    rsuminv[t] = 1.f / s;
  }
  __syncthreads();
  for (int i = t; i < 392; i += 256) {
    const int j = i / 49, m = i - j * 49;
    float a = 0.f;
#pragma unroll
    for (int jj = 0; jj < 8; ++jj) a += t2[j * 8 + jj] * (sP[jj][m] * rsuminv[jj]);
    sQ[j][m] = a;
  }
  __syncthreads();
  for (int c = t; c < NC; c += 256) {
    const int hh = c >> 6;
    const float* vp = vb + ((size_t)b * NC + c) * 49;
    float a = 0.f;
    for (int m = 0; m < 49; ++m) a += sQ[hh][m] * vp[m];
    a += vloc[((size_t)b * NC + c) * 49 + n];
    y7[((size_t)b * 49 + n) * NC + c] = a;
  }
}

// ---------------------------------------------------------------- bilinear 7->56 + hardswish -> h[100352][512] bf16 (vectorized stores)
__global__ __launch_bounds__(256) void k_resize(const float* __restrict__ y7,
                                                __hip_bfloat16* __restrict__ h) {
  const int y = blockIdx.x, b = blockIdx.y, t = threadIdx.x;
  __shared__ float L[2][7][512];
  float sy = (y - 3.5f) * 0.125f;
  sy = fminf(fmaxf(sy, 0.f), 6.f);
  const int iy0 = min((int)floorf(sy), 5);
  const float wy = sy - (float)iy0;
  const float* src = y7 + ((size_t)b * 49 + iy0 * 7) * NC;
  float* Lf = &L[0][0][0];
  for (int i = t; i < 2 * 7 * 512; i += 256) Lf[i] = src[i];
  __syncthreads();
  const size_t outb = ((size_t)b * P56 + (size_t)y * 56) * NC;
  const int c0 = t * 2;                 // 256 threads x 2 ch = 512
  for (int x = 0; x < 56; ++x) {
    float sx = (x - 3.5f) * 0.125f;
    sx = fminf(fmaxf(sx, 0.f), 6.f);
    const int ix0 = min((int)floorf(sx), 5);
    const float wx = sx - (float)ix0;
    const float w00 = (1.f - wy) * (1.f - wx), w01 = (1.f - wy) * wx;
    const float w10 = wy * (1.f - wx),         w11 = wy * wx;
    float hs[2];
#pragma unroll
    for (int j = 0; j < 2; ++j) {
      const int c = c0 + j;
      const float v = w00 * L[0][ix0][c] + w01 * L[0][ix0 + 1][c]
                    + w10 * L[1][ix0][c] + w11 * L[1][ix0 + 1][c];
      hs[j] = v * fminf(fmaxf(v + 3.f, 0.f), 6.f) * (1.f / 6.f);
    }
    __hip_bfloat162 p;
    p.x = __float2bfloat16(hs[0]);
    p.y = __float2bfloat16(hs[1]);
    *(__hip_bfloat162*)(&h[outb + (size_t)x * NC + c0]) = p;
  }
}

// ----------------------------------------------------------------
extern "C" void kernel_launch(void* const* d_in, const int* in_sizes, int n_in,
                              void* d_out, int out_size, void* d_ws, size_t ws_size,
                              hipStream_t stream) {
  (void)in_sizes; (void)n_in; (void)out_size; (void)ws_size;
  const float* x     = (const float*)d_in[0];
  const float* dw_w  = (const float*)d_in[1];
  const float* bn0_s = (const float*)d_in[2];
  const float* bn0_b = (const float*)d_in[3];
  const float* wq    = (const float*)d_in[4];
  const float* bnq_s = (const float*)d_in[5];
  const float* bnq_b = (const float*)d_in[6];
  const float* wk    = (const float*)d_in[7];
  const float* bnk_s = (const float*)d_in[8];
  const float* bnk_b = (const float*)d_in[9];
  const float* wv    = (const float*)d_in[10];
  const float* bnv_s = (const float*)d_in[11];
  const float* bnv_b = (const float*)d_in[12];
  const float* loc_w = (const float*)d_in[13];
  const float* loc_b = (const float*)d_in[14];
  const float* bnl_s = (const float*)d_in[15];
  const float* bnl_b = (const float*)d_in[16];
  const float* th1   = (const float*)d_in[17];
  const float* th2   = (const float*)d_in[18];
  const float* lsc   = (const float*)d_in[19];
  const float* ab    = (const float*)d_in[20];
  const float* wo    = (const float*)d_in[21];
  const float* bno_s = (const float*)d_in[22];
  const float* bno_b = (const float*)d_in[23];
  const int*   bidx  = (const int*)d_in[24];

  char* w = (char*)d_ws;
  auto alloc = [&](size_t bytes) {
    char* p = w;
    w += (bytes + 255) & ~(size_t)255;
    return p;
  };
  __hip_bfloat16* h_buf = (__hip_bfloat16*)alloc((size_t)NBIG * NC * 2);
  __hip_bfloat16* wq_b  = (__hip_bfloat16*)alloc((size_t)NC * NC * 2);
  __hip_bfloat16* wk_b  = (__hip_bfloat16*)alloc((size_t)NC * NC * 2);
  __hip_bfloat16* wv_b  = (__hip_bfloat16*)alloc((size_t)NC * NC * 2);
  __hip_bfloat16* wo_b  = (__hip_bfloat16*)alloc((size_t)NC * NC * 2);
  __hip_bfloat16* lw_b  = (__hip_bfloat16*)alloc((size_t)NC * KLOC * 2);
  __hip_bfloat16* xs    = (__hip_bfloat16*)alloc((size_t)NTOKP * NC * 2);  // padded rows
  float* qb   = (float*)alloc((size_t)NB * NC * 49 * 4);
  float* kb   = (float*)alloc((size_t)NB * NC * 49 * 4);
  float* vb   = (float*)alloc((size_t)NB * NC * 49 * 4);
  float* vloc = (float*)alloc((size_t)NB * NC * 49 * 4);
  float* y7   = (float*)alloc((size_t)NB * 49 * NC * 4);
  float* Sb   = (float*)alloc((size_t)NB * NHD * 49 * 49 * 4);
  // bloc aliases h_buf: bloc dies (after k_vloc_gemm) before h_buf is written (k_resize)
  __hip_bfloat16* bloc = (__hip_bfloat16*)h_buf;   // 14.5 MB << 103 MB

  k_cvt<<<dim3(128, 5), 256, 0, stream>>>(wq, wk, wv, wo, loc_w,
                                          wq_b, wk_b, wv_b, wo_b, lw_b);
  k_stride<<<dim3(NC, NB), 64, 0, stream>>>(x, dw_w, bn0_s, bn0_b, xs);
  k_gemm_qkv<<<dim3(13 * 12), 256, 0, stream>>>(wq_b, wk_b, wv_b, xs,
                                                bnq_s, bnq_b, bnk_s, bnk_b, bnv_s, bnv_b,
                                                qb, kb, vb);
  k_im2col<<<dim3(NHD, NB), 256, 0, stream>>>(vb, bloc);
  k_vloc_gemm<<<dim3(13, NHD), 256, 0, stream>>>(lw_b, bloc, loc_b, bnl_s, bnl_b, vloc);
  k_attn1<<<dim3(NHD, NB), 256, 0, stream>>>(qb, kb, lsc, ab, bidx, Sb);
  k_attn2<<<dim3(49, NB), 256, 0, stream>>>(Sb, th1, th2, vb, vloc, y7);
  k_resize<<<dim3(RES, NB), 256, 0, stream>>>(y7, h_buf);
  k_gemm_big<<<dim3(4 * 784), 256, 0, stream>>>(wo_b, h_buf, bno_s, bno_b, (float*)d_out);
}

// Round 10
// 262.498 us; speedup vs baseline: 1.0676x; 1.0606x over previous
//
#include <hip/hip_runtime.h>
#include <hip/hip_bf16.h>
#include <stdint.h>

typedef short short8 __attribute__((ext_vector_type(8)));
typedef float f32x4 __attribute__((ext_vector_type(4)));

#define NB    32
#define NC    512
#define NHD   8
#define HDD   64
#define N7    49
#define RES   56
#define P56   3136
#define NTOK  1568     // 32*49
#define NTOKP 1664     // padded to 13*128 for unguarded staging
#define NBIG  100352   // 32*3136
#define KDIM  512
#define KLOC  576      // 64ci * 9taps

// async global->LDS, 16B per lane; LDS dest is wave-uniform base + lane*16
__device__ __forceinline__ void gload_lds16(const __hip_bfloat16* g, __hip_bfloat16* l) {
  __builtin_amdgcn_global_load_lds(
      (const __attribute__((address_space(1))) void*)g,
      (__attribute__((address_space(3))) void*)l, 16, 0, 0);
}

// ---------------------------------------------------------------- fused: depthwise 3x3 stride-8 + BN0 (blocks 0..4095)
//                                                                   + fp32->bf16 weight convert (blocks 4096..4751)
__global__ __launch_bounds__(256) void k_stride_cvt(
    const float* __restrict__ x, const float* __restrict__ dw,
    const float* __restrict__ s0, const float* __restrict__ b0,
    __hip_bfloat16* __restrict__ xs,
    const float* __restrict__ c0, const float* __restrict__ c1,
    const float* __restrict__ c2, const float* __restrict__ c3,
    const float* __restrict__ c4,
    __hip_bfloat16* __restrict__ d0, __hip_bfloat16* __restrict__ d1,
    __hip_bfloat16* __restrict__ d2, __hip_bfloat16* __restrict__ d3,
    __hip_bfloat16* __restrict__ d4) {
  const int bid = blockIdx.x, t = threadIdx.x;
  if (bid >= 4096) {
    // weight convert: virtual concat of 5 segments (4x 262144 + 294912 els)
    const long base = (long)(bid - 4096) * 2048;
#pragma unroll
    for (int j = 0; j < 8; ++j) {
      long i = base + t + j * 256;
      const float* s; __hip_bfloat16* d; long off;
      if (i >= 1048576)      { s = c4; d = d4; off = i - 1048576; }
      else if (i >= 786432)  { s = c3; d = d3; off = i - 786432; }
      else if (i >= 524288)  { s = c2; d = d2; off = i - 524288; }
      else if (i >= 262144)  { s = c1; d = d1; off = i - 262144; }
      else                   { s = c0; d = d0; off = i; }
      d[off] = __float2bfloat16(s[off]);
    }
    return;
  }
  // stride part: 4096 blocks = 32 b x 128 channel-groups (4 ci each)
  const int b = bid >> 7, cig = bid & 127;
  const int sub = t >> 6, lane = t & 63;
  const int ci = cig * 4 + sub;
  __shared__ float rows[4][21][56];
  const float* xp = x + ((size_t)(b * NC + ci)) * RES * RES;
  for (int r = lane; r < 21 * 56; r += 64) {
    int rr = r / 56, cc = r - rr * 56;
    int oh = rr / 3, kh = rr - oh * 3;
    int ih = oh * 8 + kh - 1;
    rows[sub][rr][cc] = (ih >= 0) ? xp[ih * 56 + cc] : 0.f;
  }
  float w[9];
#pragma unroll
  for (int j = 0; j < 9; ++j) w[j] = dw[ci * 9 + j];
  const float sc = s0[ci], bi = b0[ci];
  __syncthreads();
  if (lane < 49) {
    const int oh = lane / 7, ow = lane - oh * 7;
    float acc = 0.f;
#pragma unroll
    for (int kh = 0; kh < 3; ++kh)
#pragma unroll
      for (int kw = 0; kw < 3; ++kw) {
        int col = ow * 8 + kw - 1;
        float v = (col >= 0) ? rows[sub][oh * 3 + kh][col] : 0.f;
        acc += v * w[kh * 3 + kw];
      }
    xs[(size_t)(b * 49 + lane) * NC + ci] = __float2bfloat16(acc * sc + bi);
  }
}

// ---------------------------------------------------------------- BIG GEMM (R6 variant — measured best <=113.6us):
// 256x256 tile, BK=32 x 16 subtiles, 2 phases/subtile (16 MFMA each,
// B-frags register-reused), 4 LDS buffers/operand, depth-2 prefetch,
// counted vmcnt(4), verified zero-conflict swizzle.
// M=512, N=100352, K=512. grid = 784 x 512 threads.
__global__ __launch_bounds__(512) void k_gemm_big(
    const __hip_bfloat16* __restrict__ A,    // [512][512] bf16
    const __hip_bfloat16* __restrict__ Bm,   // [100352][512] bf16
    const float* __restrict__ scale, const float* __restrict__ bias,
    float* __restrict__ out) {
  __shared__ __align__(16) __hip_bfloat16 lsA[4][256 * 32];
  __shared__ __align__(16) __hip_bfloat16 lsB[4][256 * 32];
  const int t = threadIdx.x;
  const int cpx = gridDim.x >> 3;
  const int nid = (blockIdx.x & 7) * cpx + (blockIdx.x >> 3);
  const int m0 = (nid & 1) * 256, n0 = (nid >> 1) * 256;

  const int lane = t & 63, wid = t >> 6;
  const int wm = (wid >> 2) * 128, wn = (wid & 3) * 64;   // 2M x 4N waves
  const int fr = lane & 15, fq = lane >> 4;
  const int rslot = (fq ^ ((fr >> 1) & 3)) * 8;           // bf16 units

  const int srow = t >> 2;                                 // 0..127
  const int scol = ((t & 3) ^ ((t >> 3) & 3)) * 8;         // bf16 units
  const __hip_bfloat16* Ab = A  + (size_t)(m0 + srow) * KDIM + scol;
  const __hip_bfloat16* Bb = Bm + (size_t)(n0 + srow) * KDIM + scol;

  const f32x4 fz = {0.f, 0.f, 0.f, 0.f};
  f32x4 acc[8][4];
#pragma unroll
  for (int i = 0; i < 8; ++i)
#pragma unroll
    for (int j = 0; j < 4; ++j) acc[i][j] = fz;

#define STA(tile, call) gload_lds16(Ab + (tile) * 32 + (size_t)(call) * 128 * KDIM, \
                                    lsA[(tile) & 3] + (call) * 4096 + wid * 512)
#define STB(tile, call) gload_lds16(Bb + (tile) * 32 + (size_t)(call) * 128 * KDIM, \
                                    lsB[(tile) & 3] + (call) * 4096 + wid * 512)

  STA(0, 0); STA(0, 1); STB(0, 0); STB(0, 1);
  STA(1, 0); STA(1, 1); STB(1, 0); STB(1, 1);
  asm volatile("s_waitcnt vmcnt(4)" ::: "memory");
  __builtin_amdgcn_sched_barrier(0);
  __builtin_amdgcn_s_barrier();
  __builtin_amdgcn_sched_barrier(0);

#pragma unroll 1
  for (int tt = 0; tt < 16; ++tt) {
    const __hip_bfloat16* lA = lsA[tt & 3];
    const __hip_bfloat16* lB = lsB[tt & 3];
    const int ft = tt + 2;

    // ---- phase A: af(rows wm..wm+63) + ALL bf -> 16 MFMA
    short8 af[4], bf[4], ag[4];
#pragma unroll
    for (int i = 0; i < 4; ++i)
      af[i] = *(const short8*)(lA + (wm + i * 16 + fr) * 32 + rslot);
#pragma unroll
    for (int j = 0; j < 4; ++j)
      bf[j] = *(const short8*)(lB + (wn + j * 16 + fr) * 32 + rslot);
    if (ft < 16) { STA(ft, 0); STA(ft, 1); }
    __builtin_amdgcn_sched_barrier(0);
    __builtin_amdgcn_s_barrier();
    asm volatile("s_waitcnt lgkmcnt(0)" ::: "memory");
    __builtin_amdgcn_sched_barrier(0);
    __builtin_amdgcn_s_setprio(1);
#pragma unroll
    for (int i = 0; i < 4; ++i)
#pragma unroll
      for (int j = 0; j < 4; ++j)
        acc[i][j] = __builtin_amdgcn_mfma_f32_16x16x32_bf16(af[i], bf[j], acc[i][j], 0, 0, 0);
    __builtin_amdgcn_s_setprio(0);
    __builtin_amdgcn_sched_barrier(0);
    __builtin_amdgcn_s_barrier();
    __builtin_amdgcn_sched_barrier(0);

    // ---- phase B: af(rows wm+64..wm+127), bf reused from registers
#pragma unroll
    for (int i = 0; i < 4; ++i)
      ag[i] = *(const short8*)(lA + (wm + 64 + i * 16 + fr) * 32 + rslot);
    if (ft < 16) { STB(ft, 0); STB(ft, 1); }
    __builtin_amdgcn_sched_barrier(0);
    __builtin_amdgcn_s_barrier();
    asm volatile("s_waitcnt lgkmcnt(0)" ::: "memory");
    __builtin_amdgcn_sched_barrier(0);
    __builtin_amdgcn_s_setprio(1);
#pragma unroll
    for (int i = 0; i < 4; ++i)
#pragma unroll
      for (int j = 0; j < 4; ++j)
        acc[4 + i][j] = __builtin_amdgcn_mfma_f32_16x16x32_bf16(ag[i], bf[j], acc[4 + i][j], 0, 0, 0);
    __builtin_amdgcn_s_setprio(0);
    __builtin_amdgcn_sched_barrier(0);

    if (tt < 14)      asm volatile("s_waitcnt vmcnt(4)" ::: "memory");
    else if (tt == 14) asm volatile("s_waitcnt vmcnt(0)" ::: "memory");
    __builtin_amdgcn_sched_barrier(0);
    __builtin_amdgcn_s_barrier();
    __builtin_amdgcn_sched_barrier(0);
  }
#undef STA
#undef STB

#pragma unroll
  for (int mi = 0; mi < 8; ++mi) {
#pragma unroll
    for (int ni = 0; ni < 4; ++ni) {
      const int gn = n0 + wn + ni * 16 + fr;
      const int outer = gn / P56;
      const int ii = gn - outer * P56;
#pragma unroll
      for (int r = 0; r < 4; ++r) {
        const int co = m0 + wm + mi * 16 + fq * 4 + r;
        out[((size_t)outer * NC + co) * P56 + ii] = acc[mi][ni][r] * scale[co] + bias[co];
      }
    }
  }
}

// ---------------------------------------------------------------- fused QKV GEMM (R8 fixed-swizzle version)
// M=1536 (3x512), N=1568(pad 1664), K=512. grid = 13*12 = 156.
__global__ __launch_bounds__(256) void k_gemm_qkv(
    const __hip_bfloat16* __restrict__ wqb, const __hip_bfloat16* __restrict__ wkb,
    const __hip_bfloat16* __restrict__ wvb, const __hip_bfloat16* __restrict__ xs,
    const float* __restrict__ sq, const float* __restrict__ bq,
    const float* __restrict__ sk, const float* __restrict__ bk,
    const float* __restrict__ sv, const float* __restrict__ bv,
    float* __restrict__ qb, float* __restrict__ kb, float* __restrict__ vb) {
  __shared__ __align__(16) __hip_bfloat16 lsA[2][128 * 32];
  __shared__ __align__(16) __hip_bfloat16 lsB[2][128 * 32];
  const int t = threadIdx.x;
  const int nwg = gridDim.x;
  const int orig = blockIdx.x;
  const int q = nwg >> 3, r = nwg & 7;
  const int xcd = orig & 7, pos = orig >> 3;
  const int nid = (xcd < r ? xcd * (q + 1) : r * (q + 1) + (xcd - r) * q) + pos;
  const int mt = nid % 12, nt = nid / 12;
  const int n0 = nt * 128, m0 = (mt & 3) * 128, sel = mt >> 2;

  const __hip_bfloat16* A = (sel == 0 ? wqb : sel == 1 ? wkb : wvb);
  const float* scale = (sel == 0 ? sq : sel == 1 ? sk : sv);
  const float* bias  = (sel == 0 ? bq : sel == 1 ? bk : bv);
  float* out = (sel == 0 ? qb : sel == 1 ? kb : vb);

  const int lane = t & 63, wid = t >> 6;
  const int wm = (wid >> 1) * 64, wn = (wid & 1) * 64;
  const int fr = lane & 15, fq = lane >> 4;
  const int rslot = (fq ^ ((fr >> 1) & 3)) * 8;
  const int srow = t >> 2;
  const int scol = ((t & 3) ^ ((t >> 3) & 3)) * 8;
  const __hip_bfloat16* Ab = A  + (size_t)(m0 + srow) * KDIM + scol;
  const __hip_bfloat16* Bb = xs + (size_t)(n0 + srow) * KDIM + scol;

  const f32x4 fz = {0.f, 0.f, 0.f, 0.f};
  f32x4 acc[4][4];
#pragma unroll
  for (int i = 0; i < 4; ++i)
#pragma unroll
    for (int j = 0; j < 4; ++j) acc[i][j] = fz;

#define STG_QKV(tile)                                                   \
  do {                                                                  \
    const int kof = (tile) * 32; const int bb = (tile) & 1;             \
    gload_lds16(Ab + kof,                       lsA[bb] + wid * 512);   \
    gload_lds16(Ab + kof + (size_t)64 * KDIM,   lsA[bb] + 2048 + wid * 512); \
    gload_lds16(Bb + kof,                       lsB[bb] + wid * 512);   \
    gload_lds16(Bb + kof + (size_t)64 * KDIM,   lsB[bb] + 2048 + wid * 512); \
  } while (0)

  STG_QKV(0);
  STG_QKV(1);
#pragma unroll 1
  for (int it = 0; it < 16; ++it) {
    if (it < 15) asm volatile("s_waitcnt vmcnt(4)" ::: "memory");
    else         asm volatile("s_waitcnt vmcnt(0)" ::: "memory");
    __builtin_amdgcn_sched_barrier(0);
    __builtin_amdgcn_s_barrier();
    __builtin_amdgcn_sched_barrier(0);
    const __hip_bfloat16* lA = lsA[it & 1];
    const __hip_bfloat16* lB = lsB[it & 1];
    short8 af[4], bf[4];
#pragma unroll
    for (int mi = 0; mi < 4; ++mi)
      af[mi] = *(const short8*)(lA + (wm + mi * 16 + fr) * 32 + rslot);
#pragma unroll
    for (int ni = 0; ni < 4; ++ni)
      bf[ni] = *(const short8*)(lB + (wn + ni * 16 + fr) * 32 + rslot);
#pragma unroll
    for (int mi = 0; mi < 4; ++mi)
#pragma unroll
      for (int ni = 0; ni < 4; ++ni)
        acc[mi][ni] = __builtin_amdgcn_mfma_f32_16x16x32_bf16(af[mi], bf[ni], acc[mi][ni], 0, 0, 0);
    __builtin_amdgcn_sched_barrier(0);
    __builtin_amdgcn_s_barrier();
    __builtin_amdgcn_sched_barrier(0);
    if (it < 14) STG_QKV(it + 2);
  }
#undef STG_QKV

#pragma unroll
  for (int mi = 0; mi < 4; ++mi) {
#pragma unroll
    for (int ni = 0; ni < 4; ++ni) {
      const int gn = n0 + wn + ni * 16 + fr;
      if (gn >= NTOK) continue;
      const int b = gn / 49, ii = gn - b * 49;
#pragma unroll
      for (int r = 0; r < 4; ++r) {
        const int co = m0 + wm + mi * 16 + fq * 4 + r;
        out[((size_t)b * NC + co) * 49 + ii] = acc[mi][ni][r] * scale[co] + bias[co];
      }
    }
  }
}

// ---------------------------------------------------------------- im2col for grouped 3x3: bloc[g][1664pad][576] bf16
__global__ __launch_bounds__(256) void k_im2col(
    const float* __restrict__ vb, __hip_bfloat16* __restrict__ bloc) {
  const int g = blockIdx.x, b = blockIdx.y, t = threadIdx.x;
  __shared__ __hip_bfloat16 pad[64][81];   // 9x9 zero-padded 7x7 grid per ci
  for (int i = t; i < 64 * 81; i += 256) pad[i / 81][i % 81] = __float2bfloat16(0.f);
  __syncthreads();
  const float* src = vb + ((size_t)b * NC + g * 64) * 49;
  for (int i = t; i < 64 * 49; i += 256) {
    const int ci = i / 49, n = i - ci * 49;
    const int oh = n / 7, ow = n - oh * 7;
    pad[ci][(oh + 1) * 9 + (ow + 1)] = __float2bfloat16(src[i]);
  }
  __syncthreads();
  __hip_bfloat16* dst = bloc + ((size_t)g * NTOKP + (size_t)b * 49) * KLOC;
  for (int i = t; i < 49 * KLOC; i += 256) {
    const int n = i / KLOC, k = i - n * KLOC;
    const int ci = k / 9, tap = k - ci * 9;
    const int kh = tap / 3, kw = tap - kh * 3;
    const int oh = n / 7, ow = n - oh * 7;
    dst[i] = pad[ci][(oh + kh) * 9 + (ow + kw)];
  }
}

// ---------------------------------------------------------------- v_local GEMM: per group, M=64, K=576, N=1568(pad 1664)
// counted ring-2 pipeline + gload_lds staging + verified swizzle.
__global__ __launch_bounds__(256) void k_vloc_gemm(
    const __hip_bfloat16* __restrict__ lwb,   // [512][576] bf16
    const __hip_bfloat16* __restrict__ bloc,  // [8][1664][576] bf16
    const float* __restrict__ lbias, const float* __restrict__ sl,
    const float* __restrict__ bl, float* __restrict__ vloc) {
  __shared__ __align__(16) __hip_bfloat16 lsA[2][64 * 32];
  __shared__ __align__(16) __hip_bfloat16 lsB[2][128 * 32];
  const int t = threadIdx.x;
  const int g = blockIdx.y;
  const int n0 = blockIdx.x * 128;
  const int lane = t & 63, wid = t >> 6;
  const int wm = (wid >> 1) * 32, wn = (wid & 1) * 64;
  const int fr = lane & 15, fq = lane >> 4;
  const int rslot = (fq ^ ((fr >> 1) & 3)) * 8;
  const int srow = t >> 2;                                 // 0..63
  const int scol = ((t & 3) ^ ((t >> 3) & 3)) * 8;
  const __hip_bfloat16* Ab = lwb  + ((size_t)g * 64 + srow) * KLOC + scol;
  const __hip_bfloat16* Bb = bloc + ((size_t)g * NTOKP + n0 + srow) * KLOC + scol;

  const f32x4 fz = {0.f, 0.f, 0.f, 0.f};
  f32x4 acc[2][4];
#pragma unroll
  for (int i = 0; i < 2; ++i)
#pragma unroll
    for (int j = 0; j < 4; ++j) acc[i][j] = fz;

#define STG_VL(tile)                                                     \
  do {                                                                   \
    const int kof = (tile) * 32; const int bb = (tile) & 1;              \
    gload_lds16(Ab + kof,                      lsA[bb] + wid * 512);     \
    gload_lds16(Bb + kof,                      lsB[bb] + wid * 512);     \
    gload_lds16(Bb + kof + (size_t)64 * KLOC,  lsB[bb] + 2048 + wid * 512); \
  } while (0)

  STG_VL(0);
  STG_VL(1);
#pragma unroll 1
  for (int it = 0; it < 18; ++it) {
    if (it < 17) asm volatile("s_waitcnt vmcnt(3)" ::: "memory");
    else         asm volatile("s_waitcnt vmcnt(0)" ::: "memory");
    __builtin_amdgcn_sched_barrier(0);
    __builtin_amdgcn_s_barrier();
    __builtin_amdgcn_sched_barrier(0);
    const __hip_bfloat16* lA = lsA[it & 1];
    const __hip_bfloat16* lB = lsB[it & 1];
    short8 af[2], bf[4];
#pragma unroll
    for (int mi = 0; mi < 2; ++mi)
      af[mi] = *(const short8*)(lA + (wm + mi * 16 + fr) * 32 + rslot);
#pragma unroll
    for (int ni = 0; ni < 4; ++ni)
      bf[ni] = *(const short8*)(lB + (wn + ni * 16 + fr) * 32 + rslot);
#pragma unroll
    for (int mi = 0; mi < 2; ++mi)
#pragma unroll
      for (int ni = 0; ni < 4; ++ni)
        acc[mi][ni] = __builtin_amdgcn_mfma_f32_16x16x32_bf16(af[mi], bf[ni], acc[mi][ni], 0, 0, 0);
    __builtin_amdgcn_sched_barrier(0);
    __builtin_amdgcn_s_barrier();
    __builtin_amdgcn_sched_barrier(0);
    if (it < 16) STG_VL(it + 2);
  }
#undef STG_VL

#pragma unroll
  for (int mi = 0; mi < 2; ++mi) {
#pragma unroll
    for (int ni = 0; ni < 4; ++ni) {
      const int gn = n0 + wn + ni * 16 + fr;
      if (gn >= NTOK) continue;          // pad rows masked here
      const int b = gn / 49, n = gn - b * 49;
#pragma unroll
      for (int r = 0; r < 4; ++r) {
        const int oc = g * 64 + wm + mi * 16 + fq * 4 + r;
        const float sc = sl[oc];
        vloc[((size_t)b * NC + oc) * 49 + n] = acc[mi][ni][r] * sc + lbias[oc] * sc + bl[oc];
      }
    }
  }
}

// ---------------------------------------------------------------- A1: normalized QK^T * ls + bias -> S[b][h][49][49]
__global__ __launch_bounds__(256) void k_attn1(
    const float* __restrict__ qb, const float* __restrict__ kb,
    const float* __restrict__ lsc, const float* __restrict__ ab, const int* __restrict__ bidx,
    float* __restrict__ Sbuf) {
  const int h = blockIdx.x, b = blockIdx.y, t = threadIdx.x;
  __shared__ float qt[64 * 49], kt[64 * 49], nq[49], abl[49];
  const float* qs = qb + ((size_t)b * NC + h * 64) * 49;
  const float* ks = kb + ((size_t)b * NC + h * 64) * 49;
  for (int i = t; i < 64 * 49; i += 256) { qt[i] = qs[i]; kt[i] = ks[i]; }
  if (t < 49) abl[t] = ab[h * 49 + t];
  __syncthreads();
  if (t < 49) {                       // q norm per token (over d)
    float s = 0.f;
    for (int d = 0; d < 64; ++d) { float v = qt[d * 49 + t]; s += v * v; }
    nq[t] = fmaxf(sqrtf(s), 1e-12f);
  } else if (t >= 64 && t < 128) {    // k norm per channel (over tokens), normalize in place
    const int d = t - 64;
    float s = 0.f;
    for (int m = 0; m < 49; ++m) { float v = kt[d * 49 + m]; s += v * v; }
    const float inv = 1.f / fmaxf(sqrtf(s), 1e-12f);
    for (int m = 0; m < 49; ++m) kt[d * 49 + m] *= inv;
  }
  __syncthreads();
  const float ls = expf(fminf(lsc[h], logf(100.f)));
  for (int idx = t; idx < 49 * 49; idx += 256) {
    const int n = idx / 49, m = idx - n * 49;
    float acc = 0.f;
    for (int d = 0; d < 64; ++d) acc += qt[d * 49 + n] * kt[d * 49 + m];
    Sbuf[(((size_t)b * NHD + h) * 49 + n) * 49 + m] = acc / nq[n] * ls + abl[bidx[idx]];
  }
}

// ---------------------------------------------------------------- A2: th1 -> softmax -> th2 -> PV + vloc -> y7[b][n][c]
__global__ __launch_bounds__(256) void k_attn2(
    const float* __restrict__ Sbuf, const float* __restrict__ th1, const float* __restrict__ th2,
    const float* __restrict__ vb, const float* __restrict__ vloc, float* __restrict__ y7) {
  const int n = blockIdx.x, b = blockIdx.y, t = threadIdx.x;
  __shared__ float sS[8][49], sP[8][49], sQ[8][49];
  __shared__ float t1[64], t2[64], rsuminv[8];
  if (t < 64) { t1[t] = th1[t]; t2[t] = th2[t]; }
  for (int i = t; i < 392; i += 256) {
    const int j = i / 49, m = i - j * 49;
    sS[j][m] = Sbuf[(((size_t)b * NHD + j) * 49 + n) * 49 + m];
  }
  __syncthreads();
  for (int i = t; i < 392; i += 256) {
    const int j = i / 49, m = i - j * 49;
    float a = 0.f;
#pragma unroll
    for (int jj = 0; jj < 8; ++jj) a += t1[j * 8 + jj] * sS[jj][m];
    sP[j][m] = a;
  }
  __syncthreads();
  if (t < 8) {
    float mx = -1e30f;
    for (int m = 0; m < 49; ++m) mx = fmaxf(mx, sP[t][m]);
    float s = 0.f;
    for (int m = 0; m < 49; ++m) { float e = expf(sP[t][m] - mx); sP[t][m] = e; s += e; }
    rsuminv[t] = 1.f / s;
  }
  __syncthreads();
  for (int i = t; i < 392; i += 256) {
    const int j = i / 49, m = i - j * 49;
    float a = 0.f;
#pragma unroll
    for (int jj = 0; jj < 8; ++jj) a += t2[j * 8 + jj] * (sP[jj][m] * rsuminv[jj]);
    sQ[j][m] = a;
  }
  __syncthreads();
  for (int c = t; c < NC; c += 256) {
    const int hh = c >> 6;
    const float* vp = vb + ((size_t)b * NC + c) * 49;
    float a = 0.f;
    for (int m = 0; m < 49; ++m) a += sQ[hh][m] * vp[m];
    a += vloc[((size_t)b * NC + c) * 49 + n];
    y7[((size_t)b * 49 + n) * NC + c] = a;
  }
}

// ---------------------------------------------------------------- bilinear 7->56 + hardswish -> h[100352][512] bf16
__global__ __launch_bounds__(256) void k_resize(const float* __restrict__ y7,
                                                __hip_bfloat16* __restrict__ h) {
  const int y = blockIdx.x, b = blockIdx.y, t = threadIdx.x;
  __shared__ float L[2][7][512];
  float sy = (y - 3.5f) * 0.125f;
  sy = fminf(fmaxf(sy, 0.f), 6.f);
  const int iy0 = min((int)floorf(sy), 5);
  const float wy = sy - (float)iy0;
  const float* src = y7 + ((size_t)b * 49 + iy0 * 7) * NC;
  float* Lf = &L[0][0][0];
  for (int i = t; i < 2 * 7 * 512; i += 256) Lf[i] = src[i];
  __syncthreads();
  const size_t outb = ((size_t)b * P56 + (size_t)y * 56) * NC;
  const int c0 = t * 2;                 // 256 threads x 2 ch = 512
  for (int x = 0; x < 56; ++x) {
    float sx = (x - 3.5f) * 0.125f;
    sx = fminf(fmaxf(sx, 0.f), 6.f);
    const int ix0 = min((int)floorf(sx), 5);
    const float wx = sx - (float)ix0;
    const float w00 = (1.f - wy) * (1.f - wx), w01 = (1.f - wy) * wx;
    const float w10 = wy * (1.f - wx),         w11 = wy * wx;
    float hs[2];
#pragma unroll
    for (int j = 0; j < 2; ++j) {
      const int c = c0 + j;
      const float v = w00 * L[0][ix0][c] + w01 * L[0][ix0 + 1][c]
                    + w10 * L[1][ix0][c] + w11 * L[1][ix0 + 1][c];
      hs[j] = v * fminf(fmaxf(v + 3.f, 0.f), 6.f) * (1.f / 6.f);
    }
    __hip_bfloat162 p;
    p.x = __float2bfloat16(hs[0]);
    p.y = __float2bfloat16(hs[1]);
    *(__hip_bfloat162*)(&h[outb + (size_t)x * NC + c0]) = p;
  }
}

// ----------------------------------------------------------------
extern "C" void kernel_launch(void* const* d_in, const int* in_sizes, int n_in,
                              void* d_out, int out_size, void* d_ws, size_t ws_size,
                              hipStream_t stream) {
  (void)in_sizes; (void)n_in; (void)out_size; (void)ws_size;
  const float* x     = (const float*)d_in[0];
  const float* dw_w  = (const float*)d_in[1];
  const float* bn0_s = (const float*)d_in[2];
  const float* bn0_b = (const float*)d_in[3];
  const float* wq    = (const float*)d_in[4];
  const float* bnq_s = (const float*)d_in[5];
  const float* bnq_b = (const float*)d_in[6];
  const float* wk    = (const float*)d_in[7];
  const float* bnk_s = (const float*)d_in[8];
  const float* bnk_b = (const float*)d_in[9];
  const float* wv    = (const float*)d_in[10];
  const float* bnv_s = (const float*)d_in[11];
  const float* bnv_b = (const float*)d_in[12];
  const float* loc_w = (const float*)d_in[13];
  const float* loc_b = (const float*)d_in[14];
  const float* bnl_s = (const float*)d_in[15];
  const float* bnl_b = (const float*)d_in[16];
  const float* th1   = (const float*)d_in[17];
  const float* th2   = (const float*)d_in[18];
  const float* lsc   = (const float*)d_in[19];
  const float* ab    = (const float*)d_in[20];
  const float* wo    = (const float*)d_in[21];
  const float* bno_s = (const float*)d_in[22];
  const float* bno_b = (const float*)d_in[23];
  const int*   bidx  = (const int*)d_in[24];

  char* w = (char*)d_ws;
  auto alloc = [&](size_t bytes) {
    char* p = w;
    w += (bytes + 255) & ~(size_t)255;
    return p;
  };
  __hip_bfloat16* h_buf = (__hip_bfloat16*)alloc((size_t)NBIG * NC * 2);
  __hip_bfloat16* wq_b  = (__hip_bfloat16*)alloc((size_t)NC * NC * 2);
  __hip_bfloat16* wk_b  = (__hip_bfloat16*)alloc((size_t)NC * NC * 2);
  __hip_bfloat16* wv_b  = (__hip_bfloat16*)alloc((size_t)NC * NC * 2);
  __hip_bfloat16* wo_b  = (__hip_bfloat16*)alloc((size_t)NC * NC * 2);
  __hip_bfloat16* lw_b  = (__hip_bfloat16*)alloc((size_t)NC * KLOC * 2);
  __hip_bfloat16* xs    = (__hip_bfloat16*)alloc((size_t)NTOKP * NC * 2);  // padded rows
  float* qb   = (float*)alloc((size_t)NB * NC * 49 * 4);
  float* kb   = (float*)alloc((size_t)NB * NC * 49 * 4);
  float* vb   = (float*)alloc((size_t)NB * NC * 49 * 4);
  float* vloc = (float*)alloc((size_t)NB * NC * 49 * 4);
  float* y7   = (float*)alloc((size_t)NB * 49 * NC * 4);
  float* Sb   = (float*)alloc((size_t)NB * NHD * 49 * 49 * 4);
  // bloc aliases h_buf: bloc dies (after k_vloc_gemm) before h_buf is written (k_resize)
  __hip_bfloat16* bloc = (__hip_bfloat16*)h_buf;   // 8*1664*576*2 = 15.3 MB << 103 MB

  k_stride_cvt<<<dim3(4096 + 656), 256, 0, stream>>>(
      x, dw_w, bn0_s, bn0_b, xs,
      wq, wk, wv, wo, loc_w, wq_b, wk_b, wv_b, wo_b, lw_b);
  k_gemm_qkv<<<dim3(13 * 12), 256, 0, stream>>>(wq_b, wk_b, wv_b, xs,
                                                bnq_s, bnq_b, bnk_s, bnk_b, bnv_s, bnv_b,
                                                qb, kb, vb);
  k_im2col<<<dim3(NHD, NB), 256, 0, stream>>>(vb, bloc);
  k_vloc_gemm<<<dim3(13, NHD), 256, 0, stream>>>(lw_b, bloc, loc_b, bnl_s, bnl_b, vloc);
  k_attn1<<<dim3(NHD, NB), 256, 0, stream>>>(qb, kb, lsc, ab, bidx, Sb);
  k_attn2<<<dim3(49, NB), 256, 0, stream>>>(Sb, th1, th2, vb, vloc, y7);
  k_resize<<<dim3(RES, NB), 256, 0, stream>>>(y7, h_buf);
  k_gemm_big<<<dim3(784), 512, 0, stream>>>(wo_b, h_buf, bno_s, bno_b, (float*)d_out);
}